// Round 2
// baseline (200.876 us; speedup 1.0000x reference)
//
#include <hip/hip_runtime.h>

// DAG MLP: L=8 layers, D=64, B=262144, 28 all-to-all forward connections.
// outs[j] += relu(outs[i] @ W_c^T + b_c), output = outs[7].
// v2: phase-per-target-layer schedule. Each wave owns 32 batch rows; all 7
// intermediate activations live as bf16 MFMA A-fragments in registers.
// Weights for phase j (j matrices) are staged into double-buffered LDS via
// global_load_lds(16B) from a PRE-SWIZZLED bf16 image in d_ws; prefetch for
// phase j+1 issues at the top of phase j. One __syncthreads per phase.

#define DD 64
#define NCONN 28
#define THREADS 512
#define ROWS_PER_WAVE 32
#define ROWS_PER_BLOCK 256     // 8 waves * 32 rows
#define MAXW 7                 // max matrices per phase
#define MAT_ELEMS 4096         // 64*64

typedef __bf16 bf16x8 __attribute__((ext_vector_type(8)));
typedef float f32x4 __attribute__((ext_vector_type(4)));
typedef unsigned short u16x8 __attribute__((ext_vector_type(8)));

__device__ __forceinline__ unsigned short f2bfu(float f) {
    return __builtin_bit_cast(unsigned short, (__bf16)f);
}

__device__ __forceinline__ void gll16(const unsigned short* g, unsigned short* l) {
    __builtin_amdgcn_global_load_lds(
        (const __attribute__((address_space(1))) unsigned int*)g,
        (__attribute__((address_space(3))) unsigned int*)l, 16, 0, 0);
}

// fp32 W -> bf16, PRE-SWIZZLED image: img[c][r*64 + (k ^ ((r&7)<<3))] = W[c][r][k]
// so a lane-linear global_load_lds copy reproduces the swizzled LDS layout.
__global__ void wconv_kernel(const float* __restrict__ w,
                             unsigned short* __restrict__ o) {
    int i = blockIdx.x * blockDim.x + threadIdx.x;   // one 8-elem chunk each
    if (i >= NCONN * 512) return;
    int conn = i >> 9;
    int within = i & 511;
    int r  = within >> 3;
    int k0 = (within & 7) << 3;
    const float* src = w + conn * MAT_ELEMS + r * DD + k0;
    float4 v0 = *reinterpret_cast<const float4*>(src);
    float4 v1 = *reinterpret_cast<const float4*>(src + 4);
    u16x8 d;
    d[0] = f2bfu(v0.x); d[1] = f2bfu(v0.y); d[2] = f2bfu(v0.z); d[3] = f2bfu(v0.w);
    d[4] = f2bfu(v1.x); d[5] = f2bfu(v1.y); d[6] = f2bfu(v1.z); d[7] = f2bfu(v1.w);
    o[0]; // no-op
    *reinterpret_cast<u16x8*>(o + conn * MAT_ELEMS + r * DD + (k0 ^ ((r & 7) << 3))) = d;
}

template <bool GLL>
__global__ __launch_bounds__(THREADS, 2)
void dag_kernel(const float* __restrict__ x,
                const float* __restrict__ Wf,
                const unsigned short* __restrict__ Wbf,
                const float* __restrict__ bs,
                float* __restrict__ out) {
    extern __shared__ char smem[];
    unsigned short* wbuf = (unsigned short*)smem;              // [2][7][4096] = 112 KB
    unsigned short* sB   = (unsigned short*)(smem + 114688);   // [8][1024]    =  16 KB
    // total 131072 B

    const int tid  = threadIdx.x;
    const int lane = tid & 63;
    const int wv   = tid >> 6;
    const int l15  = lane & 15;
    const int kg   = lane >> 4;

    constexpr int OFFS[7] = {0, 7, 13, 18, 22, 25, 27};  // c(i->j) = OFFS[i] + (j-i-1)

    const long rowbase = (long)blockIdx.x * ROWS_PER_BLOCK + wv * ROWS_PER_WAVE;

    bf16x8 afrag[7][2][2];   // [src layer][rowtile][kstep]

    // layer 0 = x
#pragma unroll
    for (int rt = 0; rt < 2; ++rt) {
        const float* xr = x + (rowbase + rt * 16 + l15) * DD;
#pragma unroll
        for (int s = 0; s < 2; ++s) {
            float4 v0 = *reinterpret_cast<const float4*>(xr + s * 32 + kg * 8);
            float4 v1 = *reinterpret_cast<const float4*>(xr + s * 32 + kg * 8 + 4);
            bf16x8 f;
            f[0] = (__bf16)v0.x; f[1] = (__bf16)v0.y; f[2] = (__bf16)v0.z; f[3] = (__bf16)v0.w;
            f[4] = (__bf16)v1.x; f[5] = (__bf16)v1.y; f[6] = (__bf16)v1.z; f[7] = (__bf16)v1.w;
            afrag[0][rt][s] = f;
        }
    }

    // prologue: stage phase-1 weights (conn 0) into buffer 0
    if constexpr (GLL) {
        gll16(Wbf + 0 * MAT_ELEMS + wv * 512 + lane * 8,
              wbuf + 0 + wv * 512);
    } else {
        const float* wp = Wf + 0 * MAT_ELEMS + tid * 8;
        float4 a0 = *reinterpret_cast<const float4*>(wp);
        float4 a1 = *reinterpret_cast<const float4*>(wp + 4);
        u16x8 d;
        d[0] = f2bfu(a0.x); d[1] = f2bfu(a0.y); d[2] = f2bfu(a0.z); d[3] = f2bfu(a0.w);
        d[4] = f2bfu(a1.x); d[5] = f2bfu(a1.y); d[6] = f2bfu(a1.z); d[7] = f2bfu(a1.w);
        int r = tid >> 3, k0b = (tid & 7) << 3;
        *reinterpret_cast<u16x8*>(wbuf + r * DD + (k0b ^ ((r & 7) << 3))) = d;
    }
    __syncthreads();

    int cur = 0;
    unsigned short* myB = sB + wv * 1024;   // 16 rows x 64 cols, reused per rowtile

#pragma unroll
    for (int j = 1; j <= 7; ++j) {
        // prefetch phase j+1 into the other buffer (freed by last barrier)
        if (j < 7) {
            const int dstoff = (cur ^ 1) * (MAXW * MAT_ELEMS);
#pragma unroll
            for (int i2 = 0; i2 <= j; ++i2) {
                const int c2 = OFFS[i2] + (j - i2);
                if constexpr (GLL) {
                    gll16(Wbf + c2 * MAT_ELEMS + wv * 512 + lane * 8,
                          wbuf + dstoff + i2 * MAT_ELEMS + wv * 512);
                } else {
                    const float* wp = Wf + c2 * MAT_ELEMS + tid * 8;
                    float4 a0 = *reinterpret_cast<const float4*>(wp);
                    float4 a1 = *reinterpret_cast<const float4*>(wp + 4);
                    u16x8 d;
                    d[0] = f2bfu(a0.x); d[1] = f2bfu(a0.y); d[2] = f2bfu(a0.z); d[3] = f2bfu(a0.w);
                    d[4] = f2bfu(a1.x); d[5] = f2bfu(a1.y); d[6] = f2bfu(a1.z); d[7] = f2bfu(a1.w);
                    int r = tid >> 3, k0b = (tid & 7) << 3;
                    *reinterpret_cast<u16x8*>(wbuf + dstoff + i2 * MAT_ELEMS +
                                              r * DD + (k0b ^ ((r & 7) << 3))) = d;
                }
            }
        }

        f32x4 acc[2][4];
#pragma unroll
        for (int rt = 0; rt < 2; ++rt)
#pragma unroll
            for (int t = 0; t < 4; ++t) {
                acc[rt][t][0] = 0.f; acc[rt][t][1] = 0.f;
                acc[rt][t][2] = 0.f; acc[rt][t][3] = 0.f;
            }

#pragma unroll
        for (int i = 0; i < j; ++i) {
            const int c = OFFS[i] + (j - i - 1);
            const unsigned short* wsl = wbuf + cur * (MAXW * MAT_ELEMS) + i * MAT_ELEMS;
            u16x8 rw[2][4];
#pragma unroll
            for (int t = 0; t < 4; ++t) {
                const int n  = t * 16 + l15;
                const int xo = (n & 7) << 3;
                rw[0][t] = *reinterpret_cast<const u16x8*>(wsl + n * DD + ((kg * 8) ^ xo));
                rw[1][t] = *reinterpret_cast<const u16x8*>(wsl + n * DD + ((32 + kg * 8) ^ xo));
            }
#pragma unroll
            for (int t = 0; t < 4; ++t) {
                const float bv = bs[c * DD + t * 16 + l15];
#pragma unroll
                for (int rt = 0; rt < 2; ++rt) {
                    f32x4 C = {bv, bv, bv, bv};
                    C = __builtin_amdgcn_mfma_f32_16x16x32_bf16(
                            afrag[i][rt][0], __builtin_bit_cast(bf16x8, rw[0][t]), C, 0, 0, 0);
                    C = __builtin_amdgcn_mfma_f32_16x16x32_bf16(
                            afrag[i][rt][1], __builtin_bit_cast(bf16x8, rw[1][t]), C, 0, 0, 0);
                    acc[rt][t][0] += fmaxf(C[0], 0.f);
                    acc[rt][t][1] += fmaxf(C[1], 0.f);
                    acc[rt][t][2] += fmaxf(C[2], 0.f);
                    acc[rt][t][3] += fmaxf(C[3], 0.f);
                }
            }
        }

        if (j < 7) {
            // D-layout -> A-frag layout via wave-private 2KB bounce, per rowtile
#pragma unroll
            for (int rt = 0; rt < 2; ++rt) {
#pragma unroll
                for (int t = 0; t < 4; ++t) {
                    const int n = t * 16 + l15;
#pragma unroll
                    for (int q = 0; q < 4; ++q) {
                        const int mr = kg * 4 + q;
                        myB[mr * DD + (n ^ ((mr & 7) << 3))] = f2bfu(acc[rt][t][q]);
                    }
                }
                asm volatile("s_waitcnt lgkmcnt(0)" ::: "memory");
#pragma unroll
                for (int s = 0; s < 2; ++s) {
                    u16x8 ra = *reinterpret_cast<const u16x8*>(
                        &myB[l15 * DD + (((s * 32 + kg * 8)) ^ ((l15 & 7) << 3))]);
                    afrag[j][rt][s] = __builtin_bit_cast(bf16x8, ra);
                }
                asm volatile("s_waitcnt lgkmcnt(0)" ::: "memory");
            }
        } else {
            float* orow = out + rowbase * DD;
#pragma unroll
            for (int rt = 0; rt < 2; ++rt)
#pragma unroll
                for (int t = 0; t < 4; ++t)
#pragma unroll
                    for (int q = 0; q < 4; ++q)
                        orow[(rt * 16 + kg * 4 + q) * DD + t * 16 + l15] = acc[rt][t][q];
        }

        __syncthreads();   // drains vmcnt (phase j+1 gll) + publishes buffers
        cur ^= 1;
    }
}

extern "C" void kernel_launch(void* const* d_in, const int* in_sizes, int n_in,
                              void* d_out, int out_size, void* d_ws, size_t ws_size,
                              hipStream_t stream) {
    const float* x  = (const float*)d_in[0];
    const float* Ws = (const float*)d_in[1];
    const float* bs = (const float*)d_in[2];
    float* out = (float*)d_out;

    const int nrows = in_sizes[0] / DD;            // 262144
    const int grid  = nrows / ROWS_PER_BLOCK;      // 1024
    const size_t lds = 131072;

    const size_t wbf_bytes = (size_t)NCONN * MAT_ELEMS * sizeof(unsigned short);
    if (ws_size >= wbf_bytes) {
        unsigned short* wbf = (unsigned short*)d_ws;
        wconv_kernel<<<(NCONN * 512 + 255) / 256, 256, 0, stream>>>(Ws, wbf);
        dag_kernel<true><<<grid, THREADS, lds, stream>>>(x, Ws, wbf, bs, out);
    } else {
        dag_kernel<false><<<grid, THREADS, lds, stream>>>(x, Ws, nullptr, bs, out);
    }
}

// Round 3
// 110.145 us; speedup vs baseline: 1.8237x; 1.8237x over previous
//
#include <hip/hip_runtime.h>

// DAG MLP: L=8 layers, D=64, B=262144, 28 all-to-all forward connections.
// outs[j] += relu(outs[i] @ W_c^T + b_c), output = outs[7].
// v3: 32 rows/wave, 4 waves/block (128 rows/block, grid 2048). All 7
// intermediate activations live as bf16 MFMA A-fragments (112 VGPR). Weights
// stream through a 4-slot LDS ring (8KB/slot) in COMPUTE order, prefetched
// depth-3 via global_load_lds(16B) from a pre-swizzled bf16 image in d_ws.
// Raw s_barrier + counted vmcnt(4/2/0) — never drain to 0 in the loop.
// Biases staged in LDS so the main loop has no global loads (exact vmcnt).

#define DD 64
#define NCONN 28
#define THREADS 256
#define ROWS_PER_WAVE 32
#define ROWS_PER_BLOCK 128     // 4 waves * 32 rows
#define MAT_ELEMS 4096         // 64*64
#define SLOT_ELEMS 4096

typedef __bf16 bf16x8 __attribute__((ext_vector_type(8)));
typedef float f32x4 __attribute__((ext_vector_type(4)));
typedef unsigned short u16x8 __attribute__((ext_vector_type(8)));

// c(i->j) = OFFS[i] + (j-i-1); CONN[p] = connection at compute position p
// (phases j=1..7, sources i ascending within phase).
__device__ constexpr int OFFS[7] = {0, 7, 13, 18, 22, 25, 27};
__device__ constexpr int CONN[28] = {0, 1,7, 2,8,13, 3,9,14,18, 4,10,15,19,22,
                                     5,11,16,20,23,25, 6,12,17,21,24,26,27};

__device__ __forceinline__ unsigned short f2bfu(float f) {
    return __builtin_bit_cast(unsigned short, (__bf16)f);
}

__device__ __forceinline__ void gll16(const unsigned short* g, unsigned short* l) {
    __builtin_amdgcn_global_load_lds(
        (const __attribute__((address_space(1))) unsigned int*)g,
        (__attribute__((address_space(3))) unsigned int*)l, 16, 0, 0);
}

// Wait keeping the newest prefetches in flight; n is compile-time after unroll.
__device__ __forceinline__ void ring_wait(int p) {
    if (p < 3) return;                 // prologue-staged, already drained
    else if (p <= 25) asm volatile("s_waitcnt vmcnt(4)" ::: "memory");
    else if (p == 26) asm volatile("s_waitcnt vmcnt(2)" ::: "memory");
    else              asm volatile("s_waitcnt vmcnt(0)" ::: "memory");
}

// fp32 W -> bf16 PRE-SWIZZLED image: img[c][r*64 + (k ^ ((r&7)<<3))] = W[c][r][k]
// so a lane-linear global_load_lds copy reproduces the swizzled LDS layout.
__global__ void wconv_kernel(const float* __restrict__ w,
                             unsigned short* __restrict__ o) {
    int i = blockIdx.x * blockDim.x + threadIdx.x;   // one 8-elem chunk each
    if (i >= NCONN * 512) return;
    int conn = i >> 9;
    int within = i & 511;
    int r  = within >> 3;
    int k0 = (within & 7) << 3;
    const float* src = w + conn * MAT_ELEMS + r * DD + k0;
    float4 v0 = *reinterpret_cast<const float4*>(src);
    float4 v1 = *reinterpret_cast<const float4*>(src + 4);
    u16x8 d;
    d[0] = f2bfu(v0.x); d[1] = f2bfu(v0.y); d[2] = f2bfu(v0.z); d[3] = f2bfu(v0.w);
    d[4] = f2bfu(v1.x); d[5] = f2bfu(v1.y); d[6] = f2bfu(v1.z); d[7] = f2bfu(v1.w);
    *reinterpret_cast<u16x8*>(o + conn * MAT_ELEMS + r * DD + (k0 ^ ((r & 7) << 3))) = d;
}

template <bool GLL>
__global__ __launch_bounds__(THREADS, 2)
void dag_kernel(const float* __restrict__ x,
                const float* __restrict__ Wf,
                const unsigned short* __restrict__ Wimg,
                const float* __restrict__ bs,
                float* __restrict__ out) {
    __shared__ __align__(16) unsigned short ring[4 * SLOT_ELEMS];   // 32 KB
    __shared__ __align__(16) unsigned short sB[4 * 1024];           //  8 KB bounce
    __shared__ __align__(16) float sBias[NCONN * DD];               //  7 KB

    const int tid  = threadIdx.x;
    const int lane = tid & 63;
    const int wv   = tid >> 6;
    const int l15  = lane & 15;
    const int kg   = lane >> 4;

    const long rowbase = (long)blockIdx.x * ROWS_PER_BLOCK + wv * ROWS_PER_WAVE;

    // ---- prologue: bias -> LDS, x -> afrag[0], stage ring slots 0..2 ----
    for (int idx = tid; idx < NCONN * DD / 4; idx += THREADS)
        reinterpret_cast<float4*>(sBias)[idx] = reinterpret_cast<const float4*>(bs)[idx];

    bf16x8 afrag[7][2][2];   // [src layer][rowtile][kstep]
#pragma unroll
    for (int rt = 0; rt < 2; ++rt) {
        const float* xr = x + (rowbase + rt * 16 + l15) * DD;
#pragma unroll
        for (int s = 0; s < 2; ++s) {
            float4 v0 = *reinterpret_cast<const float4*>(xr + s * 32 + kg * 8);
            float4 v1 = *reinterpret_cast<const float4*>(xr + s * 32 + kg * 8 + 4);
            bf16x8 f;
            f[0] = (__bf16)v0.x; f[1] = (__bf16)v0.y; f[2] = (__bf16)v0.z; f[3] = (__bf16)v0.w;
            f[4] = (__bf16)v1.x; f[5] = (__bf16)v1.y; f[6] = (__bf16)v1.z; f[7] = (__bf16)v1.w;
            afrag[0][rt][s] = f;
        }
    }

    auto stage_gll = [&](int p) {
        const unsigned short* src = Wimg + CONN[p] * MAT_ELEMS + wv * 512 + lane * 8;
        unsigned short* dst = ring + (p & 3) * SLOT_ELEMS + wv * 512;
#pragma unroll
        for (int h = 0; h < 2; ++h)
            gll16(src + h * 2048, dst + h * 2048);
    };
    auto stage_direct = [&](int p) {   // fallback: fp32 -> bf16 reg staging
        const float* wp = Wf + CONN[p] * MAT_ELEMS;
#pragma unroll
        for (int h = 0; h < 2; ++h) {
            const int e0 = h * 2048 + tid * 8;
            float4 a0 = *reinterpret_cast<const float4*>(wp + e0);
            float4 a1 = *reinterpret_cast<const float4*>(wp + e0 + 4);
            u16x8 d;
            d[0] = f2bfu(a0.x); d[1] = f2bfu(a0.y); d[2] = f2bfu(a0.z); d[3] = f2bfu(a0.w);
            d[4] = f2bfu(a1.x); d[5] = f2bfu(a1.y); d[6] = f2bfu(a1.z); d[7] = f2bfu(a1.w);
            const int r = e0 >> 6, k0 = e0 & 63;
            *reinterpret_cast<u16x8*>(ring + (p & 3) * SLOT_ELEMS +
                                      r * DD + (k0 ^ ((r & 7) << 3))) = d;
        }
    };

    if constexpr (GLL) { stage_gll(0); stage_gll(1); stage_gll(2); }
    __syncthreads();   // publishes bias LDS (+ drains prologue glls): 0 outstanding

    unsigned short* myB = sB + wv * 1024;

#pragma unroll
    for (int j = 1; j <= 7; ++j) {
        f32x4 acc[2][4];
#pragma unroll
        for (int rt = 0; rt < 2; ++rt)
#pragma unroll
            for (int t = 0; t < 4; ++t) {
                acc[rt][t][0] = 0.f; acc[rt][t][1] = 0.f;
                acc[rt][t][2] = 0.f; acc[rt][t][3] = 0.f;
            }

#pragma unroll
        for (int i = 0; i < j; ++i) {
            const int p = j * (j - 1) / 2 + i;      // compute position 0..27
            const int c = OFFS[i] + (j - i - 1);    // connection index

            if constexpr (GLL) {
                ring_wait(p);                        // slot p ready (mine)
                __builtin_amdgcn_s_barrier();        // slot p ready (all waves);
                __builtin_amdgcn_sched_barrier(0);   //  slot (p+3)&3 reusable
                if (p + 3 < NCONN) stage_gll(p + 3);
            } else {
                __syncthreads();
                stage_direct(p);
                __syncthreads();
            }

            const unsigned short* wsl = ring + (p & 3) * SLOT_ELEMS;
#pragma unroll
            for (int t = 0; t < 4; ++t) {
                const int n  = t * 16 + l15;
                const int xo = (n & 7) << 3;
                u16x8 rw0 = *reinterpret_cast<const u16x8*>(wsl + n * DD + ((kg * 8) ^ xo));
                u16x8 rw1 = *reinterpret_cast<const u16x8*>(wsl + n * DD + ((32 + kg * 8) ^ xo));
                const float bv = sBias[c * DD + n];
#pragma unroll
                for (int rt = 0; rt < 2; ++rt) {
                    f32x4 C = {bv, bv, bv, bv};
                    C = __builtin_amdgcn_mfma_f32_16x16x32_bf16(
                            afrag[i][rt][0], __builtin_bit_cast(bf16x8, rw0), C, 0, 0, 0);
                    C = __builtin_amdgcn_mfma_f32_16x16x32_bf16(
                            afrag[i][rt][1], __builtin_bit_cast(bf16x8, rw1), C, 0, 0, 0);
                    acc[rt][t][0] += fmaxf(C[0], 0.f);
                    acc[rt][t][1] += fmaxf(C[1], 0.f);
                    acc[rt][t][2] += fmaxf(C[2], 0.f);
                    acc[rt][t][3] += fmaxf(C[3], 0.f);
                }
            }
        }

        if (j < 7) {
            // D-layout -> A-frag layout via wave-private 2KB bounce (no barrier)
#pragma unroll
            for (int rt = 0; rt < 2; ++rt) {
#pragma unroll
                for (int t = 0; t < 4; ++t) {
                    const int n = t * 16 + l15;
#pragma unroll
                    for (int q = 0; q < 4; ++q) {
                        const int mr = kg * 4 + q;
                        myB[mr * DD + (n ^ ((mr & 7) << 3))] = f2bfu(acc[rt][t][q]);
                    }
                }
                asm volatile("s_waitcnt lgkmcnt(0)" ::: "memory");
                __builtin_amdgcn_sched_barrier(0);
#pragma unroll
                for (int s = 0; s < 2; ++s) {
                    u16x8 ra = *reinterpret_cast<const u16x8*>(
                        &myB[l15 * DD + ((s * 32 + kg * 8) ^ ((l15 & 7) << 3))]);
                    afrag[j][rt][s] = __builtin_bit_cast(bf16x8, ra);
                }
                asm volatile("s_waitcnt lgkmcnt(0)" ::: "memory");
                __builtin_amdgcn_sched_barrier(0);
            }
        } else {
            float* orow = out + rowbase * DD;
#pragma unroll
            for (int rt = 0; rt < 2; ++rt)
#pragma unroll
                for (int t = 0; t < 4; ++t)
#pragma unroll
                    for (int q = 0; q < 4; ++q)
                        orow[(rt * 16 + kg * 4 + q) * DD + t * 16 + l15] = acc[rt][t][q];
        }
    }
}

extern "C" void kernel_launch(void* const* d_in, const int* in_sizes, int n_in,
                              void* d_out, int out_size, void* d_ws, size_t ws_size,
                              hipStream_t stream) {
    const float* x  = (const float*)d_in[0];
    const float* Ws = (const float*)d_in[1];
    const float* bs = (const float*)d_in[2];
    float* out = (float*)d_out;

    const int nrows = in_sizes[0] / DD;            // 262144
    const int grid  = nrows / ROWS_PER_BLOCK;      // 2048

    const size_t wbf_bytes = (size_t)NCONN * MAT_ELEMS * sizeof(unsigned short);
    if (ws_size >= wbf_bytes) {
        unsigned short* wbf = (unsigned short*)d_ws;
        wconv_kernel<<<(NCONN * 512 + 255) / 256, 256, 0, stream>>>(Ws, wbf);
        dag_kernel<true><<<grid, THREADS, 0, stream>>>(x, Ws, wbf, bs, out);
    } else {
        dag_kernel<false><<<grid, THREADS, 0, stream>>>(x, Ws, nullptr, bs, out);
    }
}

// Round 4
// 104.791 us; speedup vs baseline: 1.9169x; 1.0511x over previous
//
#include <hip/hip_runtime.h>

// DAG MLP: L=8 layers, D=64, B=262144, 28 all-to-all forward connections.
// outs[j] += relu(outs[i] @ W_c^T + b_c), output = outs[7].
// v4: v3 data path (32 rows/wave, 4 waves/block, 4-slot LDS ring, pre-swizzled
// bf16 W image, global_load_lds 16B) with a pair-scheduled pipeline:
//   - ONE __syncthreads per connection PAIR (14 barriers total)
//   - stage glls issued right AFTER the barrier; consumed at the barrier after
//     next (issue->wait distance ~2 connections of compute > L2 latency)
//   - no sched_barrier fences in the loop; compiler free to pipeline
//   - s_setprio(1) around each connection's MFMA cluster

#define DD 64
#define NCONN 28
#define THREADS 256
#define ROWS_PER_WAVE 32
#define ROWS_PER_BLOCK 128     // 4 waves * 32 rows
#define MAT_ELEMS 4096         // 64*64

typedef __bf16 bf16x8 __attribute__((ext_vector_type(8)));
typedef float f32x4 __attribute__((ext_vector_type(4)));
typedef unsigned short u16x8 __attribute__((ext_vector_type(8)));

// c(i->j) = OFFS[i] + (j-i-1); CONN[p] = connection at compute position p
// (phases j=1..7, sources i ascending within phase).
__device__ constexpr int OFFS[7] = {0, 7, 13, 18, 22, 25, 27};
__device__ constexpr int CONN[28] = {0, 1,7, 2,8,13, 3,9,14,18, 4,10,15,19,22,
                                     5,11,16,20,23,25, 6,12,17,21,24,26,27};

__device__ __forceinline__ unsigned short f2bfu(float f) {
    return __builtin_bit_cast(unsigned short, (__bf16)f);
}

__device__ __forceinline__ void gll16(const unsigned short* g, unsigned short* l) {
    __builtin_amdgcn_global_load_lds(
        (const __attribute__((address_space(1))) unsigned int*)g,
        (__attribute__((address_space(3))) unsigned int*)l, 16, 0, 0);
}

// fp32 W -> bf16 PRE-SWIZZLED image: img[c][r*64 + (k ^ ((r&7)<<3))] = W[c][r][k]
// so a lane-linear global_load_lds copy reproduces the swizzled LDS layout.
__global__ void wconv_kernel(const float* __restrict__ w,
                             unsigned short* __restrict__ o) {
    int i = blockIdx.x * blockDim.x + threadIdx.x;   // one 8-elem chunk each
    if (i >= NCONN * 512) return;
    int conn = i >> 9;
    int within = i & 511;
    int r  = within >> 3;
    int k0 = (within & 7) << 3;
    const float* src = w + conn * MAT_ELEMS + r * DD + k0;
    float4 v0 = *reinterpret_cast<const float4*>(src);
    float4 v1 = *reinterpret_cast<const float4*>(src + 4);
    u16x8 d;
    d[0] = f2bfu(v0.x); d[1] = f2bfu(v0.y); d[2] = f2bfu(v0.z); d[3] = f2bfu(v0.w);
    d[4] = f2bfu(v1.x); d[5] = f2bfu(v1.y); d[6] = f2bfu(v1.z); d[7] = f2bfu(v1.w);
    *reinterpret_cast<u16x8*>(o + conn * MAT_ELEMS + r * DD + (k0 ^ ((r & 7) << 3))) = d;
}

template <bool GLL>
__global__ __launch_bounds__(THREADS, 2)
void dag_kernel(const float* __restrict__ x,
                const float* __restrict__ Wf,
                const unsigned short* __restrict__ Wimg,
                const float* __restrict__ bs,
                float* __restrict__ out) {
    __shared__ __align__(16) unsigned short ring[4 * MAT_ELEMS];    // 32 KB
    __shared__ __align__(16) unsigned short sB[4 * 1024];           //  8 KB bounce
    __shared__ __align__(16) float sBias[NCONN * DD];               //  7 KB

    const int tid  = threadIdx.x;
    const int lane = tid & 63;
    const int wv   = tid >> 6;
    const int l15  = lane & 15;
    const int kg   = lane >> 4;

    const long rowbase = (long)blockIdx.x * ROWS_PER_BLOCK + wv * ROWS_PER_WAVE;

    // ---- prologue: bias -> LDS, x -> afrag[0], stage slots for p0,p1 ----
    for (int idx = tid; idx < NCONN * DD / 4; idx += THREADS)
        reinterpret_cast<float4*>(sBias)[idx] = reinterpret_cast<const float4*>(bs)[idx];

    bf16x8 afrag[7][2][2];   // [src layer][rowtile][kstep]
#pragma unroll
    for (int rt = 0; rt < 2; ++rt) {
        const float* xr = x + (rowbase + rt * 16 + l15) * DD;
#pragma unroll
        for (int s = 0; s < 2; ++s) {
            float4 v0 = *reinterpret_cast<const float4*>(xr + s * 32 + kg * 8);
            float4 v1 = *reinterpret_cast<const float4*>(xr + s * 32 + kg * 8 + 4);
            bf16x8 f;
            f[0] = (__bf16)v0.x; f[1] = (__bf16)v0.y; f[2] = (__bf16)v0.z; f[3] = (__bf16)v0.w;
            f[4] = (__bf16)v1.x; f[5] = (__bf16)v1.y; f[6] = (__bf16)v1.z; f[7] = (__bf16)v1.w;
            afrag[0][rt][s] = f;
        }
    }

    auto stage_gll = [&](int p) {
        const unsigned short* src = Wimg + CONN[p] * MAT_ELEMS + wv * 512 + lane * 8;
        unsigned short* dst = ring + (p & 3) * MAT_ELEMS + wv * 512;
#pragma unroll
        for (int h = 0; h < 2; ++h)
            gll16(src + h * 2048, dst + h * 2048);
    };
    auto stage_direct = [&](int p) {   // fallback: fp32 -> bf16 reg staging
        const float* wp = Wf + CONN[p] * MAT_ELEMS;
#pragma unroll
        for (int h = 0; h < 2; ++h) {
            const int e0 = h * 2048 + tid * 8;
            float4 a0 = *reinterpret_cast<const float4*>(wp + e0);
            float4 a1 = *reinterpret_cast<const float4*>(wp + e0 + 4);
            u16x8 d;
            d[0] = f2bfu(a0.x); d[1] = f2bfu(a0.y); d[2] = f2bfu(a0.z); d[3] = f2bfu(a0.w);
            d[4] = f2bfu(a1.x); d[5] = f2bfu(a1.y); d[6] = f2bfu(a1.z); d[7] = f2bfu(a1.w);
            const int r = e0 >> 6, k0 = e0 & 63;
            *reinterpret_cast<u16x8*>(ring + (p & 3) * MAT_ELEMS +
                                      r * DD + (k0 ^ ((r & 7) << 3))) = d;
        }
    };

    if constexpr (GLL) { stage_gll(0); stage_gll(1); }
    __syncthreads();   // bias/LDS published, prologue glls drained

    unsigned short* myB = sB + wv * 1024;
    f32x4 acc[2][4];

#pragma unroll
    for (int j = 1; j <= 7; ++j) {
#pragma unroll
        for (int rt = 0; rt < 2; ++rt)
#pragma unroll
            for (int t = 0; t < 4; ++t) {
                acc[rt][t][0] = 0.f; acc[rt][t][1] = 0.f;
                acc[rt][t][2] = 0.f; acc[rt][t][3] = 0.f;
            }

#pragma unroll
        for (int i = 0; i < j; ++i) {
            const int p = j * (j - 1) / 2 + i;      // compute position 0..27
            const int c = OFFS[i] + (j - i - 1);    // connection index

            if constexpr (GLL) {
                // pair schedule: barrier once per even p; then stage pair p+2
                if ((p & 1) == 0) {
                    if (p > 0) __syncthreads();   // slots for p,p+1 ready; p-2,p-1 free
                    if (p + 2 < NCONN) stage_gll(p + 2);
                    if (p + 3 < NCONN) stage_gll(p + 3);
                }
            } else {
                __syncthreads();
                stage_direct(p);
                __syncthreads();
            }

            const unsigned short* wsl = ring + (p & 3) * MAT_ELEMS;
            __builtin_amdgcn_s_setprio(1);
#pragma unroll
            for (int t = 0; t < 4; ++t) {
                const int n  = t * 16 + l15;
                const int xo = (n & 7) << 3;
                u16x8 rw0 = *reinterpret_cast<const u16x8*>(wsl + n * DD + ((kg * 8) ^ xo));
                u16x8 rw1 = *reinterpret_cast<const u16x8*>(wsl + n * DD + ((32 + kg * 8) ^ xo));
                const float bv = sBias[c * DD + n];
#pragma unroll
                for (int rt = 0; rt < 2; ++rt) {
                    f32x4 C = {bv, bv, bv, bv};
                    C = __builtin_amdgcn_mfma_f32_16x16x32_bf16(
                            afrag[i][rt][0], __builtin_bit_cast(bf16x8, rw0), C, 0, 0, 0);
                    C = __builtin_amdgcn_mfma_f32_16x16x32_bf16(
                            afrag[i][rt][1], __builtin_bit_cast(bf16x8, rw1), C, 0, 0, 0);
                    acc[rt][t][0] += fmaxf(C[0], 0.f);
                    acc[rt][t][1] += fmaxf(C[1], 0.f);
                    acc[rt][t][2] += fmaxf(C[2], 0.f);
                    acc[rt][t][3] += fmaxf(C[3], 0.f);
                }
            }
            __builtin_amdgcn_s_setprio(0);
        }

        if (j < 7) {
            // D-layout -> A-frag layout via wave-private 2KB bounce (no barrier)
#pragma unroll
            for (int rt = 0; rt < 2; ++rt) {
#pragma unroll
                for (int t = 0; t < 4; ++t) {
                    const int n = t * 16 + l15;
#pragma unroll
                    for (int q = 0; q < 4; ++q) {
                        const int mr = kg * 4 + q;
                        myB[mr * DD + (n ^ ((mr & 7) << 3))] = f2bfu(acc[rt][t][q]);
                    }
                }
                asm volatile("s_waitcnt lgkmcnt(0)" ::: "memory");
#pragma unroll
                for (int s = 0; s < 2; ++s) {
                    u16x8 ra = *reinterpret_cast<const u16x8*>(
                        &myB[l15 * DD + ((s * 32 + kg * 8) ^ ((l15 & 7) << 3))]);
                    afrag[j][rt][s] = __builtin_bit_cast(bf16x8, ra);
                }
                asm volatile("s_waitcnt lgkmcnt(0)" ::: "memory");
            }
        } else {
            float* orow = out + rowbase * DD;
#pragma unroll
            for (int rt = 0; rt < 2; ++rt)
#pragma unroll
                for (int t = 0; t < 4; ++t)
#pragma unroll
                    for (int q = 0; q < 4; ++q)
                        orow[(rt * 16 + kg * 4 + q) * DD + t * 16 + l15] = acc[rt][t][q];
        }
    }
}

extern "C" void kernel_launch(void* const* d_in, const int* in_sizes, int n_in,
                              void* d_out, int out_size, void* d_ws, size_t ws_size,
                              hipStream_t stream) {
    const float* x  = (const float*)d_in[0];
    const float* Ws = (const float*)d_in[1];
    const float* bs = (const float*)d_in[2];
    float* out = (float*)d_out;

    const int nrows = in_sizes[0] / DD;            // 262144
    const int grid  = nrows / ROWS_PER_BLOCK;      // 2048

    const size_t wbf_bytes = (size_t)NCONN * MAT_ELEMS * sizeof(unsigned short);
    if (ws_size >= wbf_bytes) {
        unsigned short* wbf = (unsigned short*)d_ws;
        wconv_kernel<<<(NCONN * 512 + 255) / 256, 256, 0, stream>>>(Ws, wbf);
        dag_kernel<true><<<grid, THREADS, 0, stream>>>(x, Ws, wbf, bs, out);
    } else {
        dag_kernel<false><<<grid, THREADS, 0, stream>>>(x, Ws, nullptr, bs, out);
    }
}

// Round 5
// 103.740 us; speedup vs baseline: 1.9363x; 1.0101x over previous
//
#include <hip/hip_runtime.h>

// DAG MLP: L=8 layers, D=64, B=262144, 28 all-to-all forward connections.
// outs[j] += relu(outs[i] @ W_c^T + b_c), output = outs[7].
// v5 = v4 schedule (pair barriers, 4-slot ring, pre-swizzled bf16 W image,
// global_load_lds 16B, setprio around MFMA) with a minimal-VALU accumulation:
//   C_in = acc + bv   (packed f32 adds; bias+running sum ride the MFMA C)
//   D    = mfma(a0,w0, mfma-chain)          (2x 16x16x32 bf16, K=64)
//   acc  = max(D, acc)                      (packed f32 max)
// using max(S+bv+acc, acc) == acc + relu(S+bv)  (exact in f32).

#define DD 64
#define NCONN 28
#define THREADS 256
#define ROWS_PER_WAVE 32
#define ROWS_PER_BLOCK 128     // 4 waves * 32 rows
#define MAT_ELEMS 4096         // 64*64

typedef __bf16 bf16x8 __attribute__((ext_vector_type(8)));
typedef float f32x4 __attribute__((ext_vector_type(4)));
typedef unsigned short u16x8 __attribute__((ext_vector_type(8)));

// c(i->j) = OFFS[i] + (j-i-1); CONN[p] = connection at compute position p
// (phases j=1..7, sources i ascending within phase).
__device__ constexpr int OFFS[7] = {0, 7, 13, 18, 22, 25, 27};
__device__ constexpr int CONN[28] = {0, 1,7, 2,8,13, 3,9,14,18, 4,10,15,19,22,
                                     5,11,16,20,23,25, 6,12,17,21,24,26,27};

__device__ __forceinline__ unsigned short f2bfu(float f) {
    return __builtin_bit_cast(unsigned short, (__bf16)f);
}

__device__ __forceinline__ f32x4 vmax4(f32x4 a, f32x4 b) {
#if __has_builtin(__builtin_elementwise_max)
    return __builtin_elementwise_max(a, b);
#else
    f32x4 r;
    r[0] = fmaxf(a[0], b[0]); r[1] = fmaxf(a[1], b[1]);
    r[2] = fmaxf(a[2], b[2]); r[3] = fmaxf(a[3], b[3]);
    return r;
#endif
}

__device__ __forceinline__ void gll16(const unsigned short* g, unsigned short* l) {
    __builtin_amdgcn_global_load_lds(
        (const __attribute__((address_space(1))) unsigned int*)g,
        (__attribute__((address_space(3))) unsigned int*)l, 16, 0, 0);
}

// fp32 W -> bf16 PRE-SWIZZLED image: img[c][r*64 + (k ^ ((r&7)<<3))] = W[c][r][k]
// so a lane-linear global_load_lds copy reproduces the swizzled LDS layout.
__global__ void wconv_kernel(const float* __restrict__ w,
                             unsigned short* __restrict__ o) {
    int i = blockIdx.x * blockDim.x + threadIdx.x;   // one 8-elem chunk each
    if (i >= NCONN * 512) return;
    int conn = i >> 9;
    int within = i & 511;
    int r  = within >> 3;
    int k0 = (within & 7) << 3;
    const float* src = w + conn * MAT_ELEMS + r * DD + k0;
    float4 v0 = *reinterpret_cast<const float4*>(src);
    float4 v1 = *reinterpret_cast<const float4*>(src + 4);
    u16x8 d;
    d[0] = f2bfu(v0.x); d[1] = f2bfu(v0.y); d[2] = f2bfu(v0.z); d[3] = f2bfu(v0.w);
    d[4] = f2bfu(v1.x); d[5] = f2bfu(v1.y); d[6] = f2bfu(v1.z); d[7] = f2bfu(v1.w);
    *reinterpret_cast<u16x8*>(o + conn * MAT_ELEMS + r * DD + (k0 ^ ((r & 7) << 3))) = d;
}

template <bool GLL>
__global__ __launch_bounds__(THREADS, 2)
void dag_kernel(const float* __restrict__ x,
                const float* __restrict__ Wf,
                const unsigned short* __restrict__ Wimg,
                const float* __restrict__ bs,
                float* __restrict__ out) {
    __shared__ __align__(16) unsigned short ring[4 * MAT_ELEMS];    // 32 KB
    __shared__ __align__(16) unsigned short sB[4 * 1024];           //  8 KB bounce
    __shared__ __align__(16) float sBias[NCONN * DD];               //  7 KB

    const int tid  = threadIdx.x;
    const int lane = tid & 63;
    const int wv   = tid >> 6;
    const int l15  = lane & 15;
    const int kg   = lane >> 4;

    const long rowbase = (long)blockIdx.x * ROWS_PER_BLOCK + wv * ROWS_PER_WAVE;

    // ---- prologue: bias -> LDS, x -> afrag[0], stage slots for p0,p1 ----
    for (int idx = tid; idx < NCONN * DD / 4; idx += THREADS)
        reinterpret_cast<float4*>(sBias)[idx] = reinterpret_cast<const float4*>(bs)[idx];

    bf16x8 afrag[7][2][2];   // [src layer][rowtile][kstep]
#pragma unroll
    for (int rt = 0; rt < 2; ++rt) {
        const float* xr = x + (rowbase + rt * 16 + l15) * DD;
#pragma unroll
        for (int s = 0; s < 2; ++s) {
            float4 v0 = *reinterpret_cast<const float4*>(xr + s * 32 + kg * 8);
            float4 v1 = *reinterpret_cast<const float4*>(xr + s * 32 + kg * 8 + 4);
            bf16x8 f;
            f[0] = (__bf16)v0.x; f[1] = (__bf16)v0.y; f[2] = (__bf16)v0.z; f[3] = (__bf16)v0.w;
            f[4] = (__bf16)v1.x; f[5] = (__bf16)v1.y; f[6] = (__bf16)v1.z; f[7] = (__bf16)v1.w;
            afrag[0][rt][s] = f;
        }
    }

    auto stage_gll = [&](int p) {
        const unsigned short* src = Wimg + CONN[p] * MAT_ELEMS + wv * 512 + lane * 8;
        unsigned short* dst = ring + (p & 3) * MAT_ELEMS + wv * 512;
#pragma unroll
        for (int h = 0; h < 2; ++h)
            gll16(src + h * 2048, dst + h * 2048);
    };
    auto stage_direct = [&](int p) {   // fallback: fp32 -> bf16 reg staging
        const float* wp = Wf + CONN[p] * MAT_ELEMS;
#pragma unroll
        for (int h = 0; h < 2; ++h) {
            const int e0 = h * 2048 + tid * 8;
            float4 a0 = *reinterpret_cast<const float4*>(wp + e0);
            float4 a1 = *reinterpret_cast<const float4*>(wp + e0 + 4);
            u16x8 d;
            d[0] = f2bfu(a0.x); d[1] = f2bfu(a0.y); d[2] = f2bfu(a0.z); d[3] = f2bfu(a0.w);
            d[4] = f2bfu(a1.x); d[5] = f2bfu(a1.y); d[6] = f2bfu(a1.z); d[7] = f2bfu(a1.w);
            const int r = e0 >> 6, k0 = e0 & 63;
            *reinterpret_cast<u16x8*>(ring + (p & 3) * MAT_ELEMS +
                                      r * DD + (k0 ^ ((r & 7) << 3))) = d;
        }
    };

    if constexpr (GLL) { stage_gll(0); stage_gll(1); }
    __syncthreads();   // bias/LDS published, prologue glls drained

    unsigned short* myB = sB + wv * 1024;
    f32x4 acc[2][4];

#pragma unroll
    for (int j = 1; j <= 7; ++j) {
#pragma unroll
        for (int rt = 0; rt < 2; ++rt)
#pragma unroll
            for (int t = 0; t < 4; ++t) {
                acc[rt][t][0] = 0.f; acc[rt][t][1] = 0.f;
                acc[rt][t][2] = 0.f; acc[rt][t][3] = 0.f;
            }

#pragma unroll
        for (int i = 0; i < j; ++i) {
            const int p = j * (j - 1) / 2 + i;      // compute position 0..27
            const int c = OFFS[i] + (j - i - 1);    // connection index

            if constexpr (GLL) {
                // pair schedule: barrier once per even p; then stage pair p+2
                if ((p & 1) == 0) {
                    if (p > 0) __syncthreads();   // slots for p,p+1 ready; p-2,p-1 free
                    if (p + 2 < NCONN) stage_gll(p + 2);
                    if (p + 3 < NCONN) stage_gll(p + 3);
                }
            } else {
                __syncthreads();
                stage_direct(p);
                __syncthreads();
            }

            const unsigned short* wsl = ring + (p & 3) * MAT_ELEMS;
            __builtin_amdgcn_s_setprio(1);
#pragma unroll
            for (int t = 0; t < 4; ++t) {
                const int n  = t * 16 + l15;
                const int xo = (n & 7) << 3;
                u16x8 rw0 = *reinterpret_cast<const u16x8*>(wsl + n * DD + ((kg * 8) ^ xo));
                u16x8 rw1 = *reinterpret_cast<const u16x8*>(wsl + n * DD + ((32 + kg * 8) ^ xo));
                const float bv = sBias[c * DD + n];
                const f32x4 bv4 = {bv, bv, bv, bv};
#pragma unroll
                for (int rt = 0; rt < 2; ++rt) {
                    // C_in = acc + bias  (pk adds); MFMA chain carries the sum;
                    // acc = max(D, acc)  (pk maxes)  == acc + relu(S + bv).
                    f32x4 C = acc[rt][t] + bv4;
                    C = __builtin_amdgcn_mfma_f32_16x16x32_bf16(
                            afrag[i][rt][0], __builtin_bit_cast(bf16x8, rw0), C, 0, 0, 0);
                    C = __builtin_amdgcn_mfma_f32_16x16x32_bf16(
                            afrag[i][rt][1], __builtin_bit_cast(bf16x8, rw1), C, 0, 0, 0);
                    acc[rt][t] = vmax4(C, acc[rt][t]);
                }
            }
            __builtin_amdgcn_s_setprio(0);
        }

        if (j < 7) {
            // D-layout -> A-frag layout via wave-private 2KB bounce (no barrier)
#pragma unroll
            for (int rt = 0; rt < 2; ++rt) {
#pragma unroll
                for (int t = 0; t < 4; ++t) {
                    const int n = t * 16 + l15;
#pragma unroll
                    for (int q = 0; q < 4; ++q) {
                        const int mr = kg * 4 + q;
                        myB[mr * DD + (n ^ ((mr & 7) << 3))] = f2bfu(acc[rt][t][q]);
                    }
                }
                asm volatile("s_waitcnt lgkmcnt(0)" ::: "memory");
#pragma unroll
                for (int s = 0; s < 2; ++s) {
                    u16x8 ra = *reinterpret_cast<const u16x8*>(
                        &myB[l15 * DD + ((s * 32 + kg * 8) ^ ((l15 & 7) << 3))]);
                    afrag[j][rt][s] = __builtin_bit_cast(bf16x8, ra);
                }
                asm volatile("s_waitcnt lgkmcnt(0)" ::: "memory");
            }
        } else {
            float* orow = out + rowbase * DD;
#pragma unroll
            for (int rt = 0; rt < 2; ++rt)
#pragma unroll
                for (int t = 0; t < 4; ++t)
#pragma unroll
                    for (int q = 0; q < 4; ++q)
                        orow[(rt * 16 + kg * 4 + q) * DD + t * 16 + l15] = acc[rt][t][q];
        }
    }
}

extern "C" void kernel_launch(void* const* d_in, const int* in_sizes, int n_in,
                              void* d_out, int out_size, void* d_ws, size_t ws_size,
                              hipStream_t stream) {
    const float* x  = (const float*)d_in[0];
    const float* Ws = (const float*)d_in[1];
    const float* bs = (const float*)d_in[2];
    float* out = (float*)d_out;

    const int nrows = in_sizes[0] / DD;            // 262144
    const int grid  = nrows / ROWS_PER_BLOCK;      // 2048

    const size_t wbf_bytes = (size_t)NCONN * MAT_ELEMS * sizeof(unsigned short);
    if (ws_size >= wbf_bytes) {
        unsigned short* wbf = (unsigned short*)d_ws;
        wconv_kernel<<<(NCONN * 512 + 255) / 256, 256, 0, stream>>>(Ws, wbf);
        dag_kernel<true><<<grid, THREADS, 0, stream>>>(x, Ws, wbf, bs, out);
    } else {
        dag_kernel<false><<<grid, THREADS, 0, stream>>>(x, Ws, nullptr, bs, out);
    }
}